// Round 6
// baseline (309.910 us; speedup 1.0000x reference)
//
#include <hip/hip_runtime.h>

#define D 128
#define ALPHA 0.2f
#define CH 8192          // edges per chunk for count/binscatter
#define MAXB 512         // >= nbuk (391)

typedef __attribute__((ext_vector_type(8))) short bf16x8;
typedef __attribute__((ext_vector_type(4))) float f32x4;

__device__ __forceinline__ unsigned short f32_to_bf16(float f) {
    unsigned u = __float_as_uint(f);
    unsigned r = u + 0x7FFFu + ((u >> 16) & 1u);   // round-to-nearest-even
    return (unsigned short)(r >> 16);
}
__device__ __forceinline__ float bf16lo(unsigned u) {
    return __uint_as_float(u << 16);
}
__device__ __forceinline__ float bf16hi(unsigned u) {
    return __uint_as_float(u & 0xFFFF0000u);
}

// Build kTbf[144][128] bf16: rows 0..127 = kernel^T, row 128 = W_map@w1,
// row 129 = W_map@w2, rows 130..143 = 0.
__global__ __launch_bounds__(256) void k_prep(
        const float* __restrict__ Wmap, const float* __restrict__ w1,
        const float* __restrict__ w2, const float* __restrict__ kern,
        unsigned short* __restrict__ kTbf) {
    int t = threadIdx.x;
    int lane = t & 63, wv = t >> 6;
    float w1a = w1[lane], w1b = w1[64 + lane];
    float w2a = w2[lane], w2b = w2[64 + lane];
    for (int r = 0; r < 32; ++r) {
        int row = wv * 32 + r;
        float xa = Wmap[row * D + lane], xb = Wmap[row * D + 64 + lane];
        float s1 = xa * w1a + xb * w1b;
        float s2 = xa * w2a + xb * w2b;
        #pragma unroll
        for (int off = 32; off; off >>= 1) {
            s1 += __shfl_xor(s1, off);
            s2 += __shfl_xor(s2, off);
        }
        if (lane == 0) {
            kTbf[128 * D + row] = f32_to_bf16(s1);
            kTbf[129 * D + row] = f32_to_bf16(s2);
        }
    }
    for (int idx = t; idx < D * D; idx += 256) {      // kernel^T
        int k = idx >> 7, c = idx & 127;
        kTbf[c * D + k] = f32_to_bf16(kern[idx]);
    }
    for (int idx = 130 * D + t; idx < 144 * D; idx += 256) kTbf[idx] = 0;
}

// per-(WG,bucket) histogram, stored bucket-major: cnt_matT[b][wg]
__global__ __launch_bounds__(256) void k_count(
        const int* __restrict__ erow, unsigned* __restrict__ cnt_matT,
        int ne, int nbuk, int nw) {
    __shared__ unsigned cl[MAXB];
    int wg = blockIdx.x, t = threadIdx.x;
    for (int i = t; i < nbuk; i += 256) cl[i] = 0u;
    __syncthreads();
    int base = wg * CH;
    int lim = min(CH, ne - base);
    for (int i = t; i < lim; i += 256)
        atomicAdd(&cl[erow[base + i] >> 8], 1u);
    __syncthreads();
    for (int i = t; i < nbuk; i += 256)
        cnt_matT[(size_t)i * nw + wg] = cl[i];
}

// single block: bucket bases + per-(wg,bucket) exclusive offsets (both b-major)
__global__ __launch_bounds__(512) void k_scanb(
        const unsigned* __restrict__ cnt_matT, unsigned* __restrict__ off_matT,
        int* __restrict__ bstart, int nw, int nbuk, int ne) {
    __shared__ unsigned tot[512];
    int t = threadIdx.x;
    unsigned s = 0;
    if (t < nbuk) {
        const unsigned* rowp = cnt_matT + (size_t)t * nw;
        for (int w = 0; w < nw; ++w) s += rowp[w];
    }
    tot[t] = s;
    __syncthreads();
    for (int off = 1; off < 512; off <<= 1) {
        unsigned add = (t >= off) ? tot[t - off] : 0u;
        __syncthreads();
        tot[t] += add;
        __syncthreads();
    }
    unsigned base = tot[t] - s;  // exclusive
    if (t < nbuk) {
        bstart[t] = (int)base;
        unsigned run = base;
        const unsigned* rowp = cnt_matT + (size_t)t * nw;
        unsigned* orow = off_matT + (size_t)t * nw;
        for (int w = 0; w < nw; ++w) {
            orow[w] = run;
            run += rowp[w];
        }
    }
    if (t == 0) bstart[nbuk] = ne;
}

// append packed {(rlocal<<24)|col, adj_bits} into per-(WG,bucket) segments
__global__ __launch_bounds__(256) void k_binscatter(
        const int* __restrict__ erow, const int* __restrict__ ecol,
        const float* __restrict__ adj, const unsigned* __restrict__ off_matT,
        int2* __restrict__ recs, int ne, int nbuk, int nw) {
    __shared__ unsigned cur[MAXB];
    int wg = blockIdx.x, t = threadIdx.x;
    for (int i = t; i < nbuk; i += 256)
        cur[i] = off_matT[(size_t)i * nw + wg];
    __syncthreads();
    int base = wg * CH;
    int lim = min(CH, ne - base);
    for (int i = t; i < lim; i += 256) {
        int k = base + i;
        int r = erow[k];
        unsigned pos = atomicAdd(&cur[r >> 8], 1u);
        recs[pos] = make_int2(
            (int)(((unsigned)(r & 255) << 24) | (unsigned)ecol[k]),
            __float_as_int(adj[k]));
    }
}

// WG per bucket: per-row counts+scan in LDS -> rowptr; scatter {col,adj} into
// the bucket's contiguous CSR window (single-XCD L2-resident writes).
__global__ __launch_bounds__(256) void k_bucket(
        const int2* __restrict__ recs, const int* __restrict__ bstart,
        int* __restrict__ rowptr, int2* __restrict__ csr, int n, int ne) {
    __shared__ unsigned cntL[256], startL[256], fillL[256];
    int b = blockIdx.x, t = threadIdx.x;
    int rb0 = b << 8;
    int s = bstart[b], e = bstart[b + 1];
    cntL[t] = 0u;
    fillL[t] = 0u;
    __syncthreads();
    for (int i = s + t; i < e; i += 256)
        atomicAdd(&cntL[((unsigned)recs[i].x) >> 24], 1u);
    __syncthreads();
    unsigned v = cntL[t];
    startL[t] = v;
    __syncthreads();
    for (int off = 1; off < 256; off <<= 1) {
        unsigned add = (t >= off) ? startL[t - off] : 0u;
        __syncthreads();
        startL[t] += add;
        __syncthreads();
    }
    unsigned myStart = startL[t] - v;  // exclusive within bucket
    startL[t] = myStart;
    if (rb0 + t < n) rowptr[rb0 + t] = s + (int)myStart;
    if (b == 0 && t == 0) rowptr[n] = ne;
    __syncthreads();
    for (int i = s + t; i < e; i += 256) {
        int2 rc = recs[i];
        unsigned r = ((unsigned)rc.x) >> 24;
        unsigned p = atomicAdd(&fillL[r], 1u);
        csr[s + (int)startL[r] + (int)p] =
            make_int2(rc.x & 0x00FFFFFF, rc.y);
    }
}

// MFMA value-GEMM: valbf[n][128] = bf16(x @ kernel); 9th col-block computes
// sa1/sa2 (u1,u2 packed as B columns 128,129). 64 rows/block, 4 waves.
#define BM 64
#define NBLK 9
__global__ __launch_bounds__(256) void k_value_gemm(
        const float* __restrict__ x, const unsigned short* __restrict__ kTbf,
        const float* __restrict__ b1, const float* __restrict__ b2,
        unsigned short* __restrict__ valbf,
        float* __restrict__ sa1, float* __restrict__ sa2, int n) {
    __shared__ unsigned short As[BM * D];          // 16 KB, swizzled
    __shared__ unsigned short Bs[NBLK * 16 * D];   // 36 KB, swizzled
    int t = threadIdx.x;
    int rowbase = blockIdx.x * BM;
    for (int idx = t; idx < BM * 32; idx += 256) {    // float4 chunks
        int r = idx >> 5, k4 = (idx & 31) << 2;
        unsigned v0 = 0, v1 = 0;
        int grow = rowbase + r;
        if (grow < n) {
            float4 f = *(const float4*)(x + (size_t)grow * D + k4);
            v0 = (unsigned)f32_to_bf16(f.x) | ((unsigned)f32_to_bf16(f.y) << 16);
            v1 = (unsigned)f32_to_bf16(f.z) | ((unsigned)f32_to_bf16(f.w) << 16);
        }
        unsigned byte = (unsigned)(r * 256 + k4 * 2) ^ ((unsigned)(r & 7) << 4);
        *(uint2*)((char*)As + byte) = make_uint2(v0, v1);
    }
    for (int idx = t; idx < NBLK * 16 * 32; idx += 256) {  // 8B chunks
        int rowB = idx >> 5;
        uint2 v = ((const uint2*)kTbf)[idx];
        unsigned byte = (unsigned)(idx * 8) ^ ((unsigned)(rowB & 7) << 4);
        *(uint2*)((char*)Bs + byte) = v;
    }
    __syncthreads();

    int w = t >> 6, lane = t & 63;
    int arow = w * 16 + (lane & 15);
    f32x4 acc[NBLK];
    #pragma unroll
    for (int b = 0; b < NBLK; ++b) acc[b] = (f32x4){0.f, 0.f, 0.f, 0.f};
    #pragma unroll
    for (int ks = 0; ks < 4; ++ks) {
        int kk = ks * 32 + (lane >> 4) * 8;
        unsigned abyte = (unsigned)(arow * 256 + kk * 2) ^ ((unsigned)(arow & 7) << 4);
        bf16x8 af = *(const bf16x8*)((const char*)As + abyte);
        #pragma unroll
        for (int cb = 0; cb < NBLK; ++cb) {
            int brow = cb * 16 + (lane & 15);
            unsigned bbyte = (unsigned)(brow * 256 + kk * 2) ^ ((unsigned)(brow & 7) << 4);
            bf16x8 bfr = *(const bf16x8*)((const char*)Bs + bbyte);
            acc[cb] = __builtin_amdgcn_mfma_f32_16x16x32_bf16(af, bfr, acc[cb], 0, 0, 0);
        }
    }
    int col = lane & 15;
    int rbase2 = rowbase + w * 16 + (lane >> 4) * 4;
    #pragma unroll
    for (int cb = 0; cb < 8; ++cb) {
        #pragma unroll
        for (int i = 0; i < 4; ++i) {
            int grow = rbase2 + i;
            if (grow < n)
                valbf[(size_t)grow * D + cb * 16 + col] = f32_to_bf16(acc[cb][i]);
        }
    }
    if (col < 2) {   // cb=8: col0 = sa1, col1 = sa2
        float bb = (col == 0) ? b1[0] : b2[0];
        float* dst = (col == 0) ? sa1 : sa2;
        #pragma unroll
        for (int i = 0; i < 4; ++i) {
            int grow = rbase2 + i;
            if (grow < n) dst[grow] = acc[8][i] + bb;
        }
    }
}

// one wave per row: single-pass online-softmax SpMM over bf16 value rows.
// 4 value gathers in flight per j-step (2 per half-wave pair).
__global__ __launch_bounds__(256) void k_row_attn(
        const int* __restrict__ rowptr, const int2* __restrict__ csr,
        const float* __restrict__ sa1, const float* __restrict__ sa2,
        const unsigned short* __restrict__ valbf,
        const float* __restrict__ bias, float* __restrict__ out, int n) {
    int wid = (blockIdx.x * 256 + threadIdx.x) >> 6;
    int lane = threadIdx.x & 63;
    if (wid >= n) return;
    int start = rowptr[wid], end = rowptr[wid + 1];
    float sa1r = sa1[wid];
    int half = lane >> 5, sub = lane & 31;

    float m = -INFINITY, dsum = 0.f;
    float acc0 = 0.f, acc1 = 0.f, acc2 = 0.f, acc3 = 0.f;

    for (int base = start; base < end; base += 64) {
        int k = base + lane;
        int cnt = min(64, end - base);
        float s = -INFINITY;
        int c = 0;
        if (k < end) {
            int2 ca = csr[k];
            c = ca.x;
            float a = __int_as_float(ca.y);
            s = a * sa1r + a * sa2[c];
            s = (s >= 0.f) ? s : ALPHA * s;
        }
        // block max + online rescale
        float bm = s;
        #pragma unroll
        for (int off = 32; off; off >>= 1) bm = fmaxf(bm, __shfl_xor(bm, off));
        float newm = fmaxf(m, bm);
        float scale = __expf(m - newm);    // first block: exp(-inf)=0
        dsum *= scale;
        acc0 *= scale; acc1 *= scale; acc2 *= scale; acc3 *= scale;
        m = newm;
        float p = 0.f;
        if (k < end) { p = __expf(s - m); dsum += p; }

        for (int j = 0; j < cnt; j += 8) {
            int e0 = j + half,     e1 = j + 2 + half;
            int e2 = j + 4 + half, e3 = j + 6 + half;
            float p0 = __shfl(p, e0); int c0 = __shfl(c, e0);
            float p1 = __shfl(p, e1); int c1 = __shfl(c, e1);
            float p2 = __shfl(p, e2); int c2 = __shfl(c, e2);
            float p3 = __shfl(p, e3); int c3 = __shfl(c, e3);
            if (e0 >= cnt) { p0 = 0.f; c0 = 0; }
            if (e1 >= cnt) { p1 = 0.f; c1 = 0; }
            if (e2 >= cnt) { p2 = 0.f; c2 = 0; }
            if (e3 >= cnt) { p3 = 0.f; c3 = 0; }
            uint2 q0 = ((const uint2*)(valbf + (size_t)c0 * D))[sub];
            uint2 q1 = ((const uint2*)(valbf + (size_t)c1 * D))[sub];
            uint2 q2 = ((const uint2*)(valbf + (size_t)c2 * D))[sub];
            uint2 q3 = ((const uint2*)(valbf + (size_t)c3 * D))[sub];
            acc0 += p0 * bf16lo(q0.x); acc1 += p0 * bf16hi(q0.x);
            acc2 += p0 * bf16lo(q0.y); acc3 += p0 * bf16hi(q0.y);
            acc0 += p1 * bf16lo(q1.x); acc1 += p1 * bf16hi(q1.x);
            acc2 += p1 * bf16lo(q1.y); acc3 += p1 * bf16hi(q1.y);
            acc0 += p2 * bf16lo(q2.x); acc1 += p2 * bf16hi(q2.x);
            acc2 += p2 * bf16lo(q2.y); acc3 += p2 * bf16hi(q2.y);
            acc0 += p3 * bf16lo(q3.x); acc1 += p3 * bf16hi(q3.x);
            acc2 += p3 * bf16lo(q3.y); acc3 += p3 * bf16hi(q3.y);
        }
    }
    acc0 += __shfl_xor(acc0, 32);
    acc1 += __shfl_xor(acc1, 32);
    acc2 += __shfl_xor(acc2, 32);
    acc3 += __shfl_xor(acc3, 32);
    #pragma unroll
    for (int off = 32; off; off >>= 1) dsum += __shfl_xor(dsum, off);
    float inv = (dsum > 0.f) ? 1.f / dsum : 0.f;   // empty row -> out = bias

    if (half == 0) {
        size_t o = (size_t)wid * D + (size_t)sub * 4;
        float4 bv = *(const float4*)(bias + o);
        float4 ov;
        ov.x = acc0 * inv + bv.x;
        ov.y = acc1 * inv + bv.y;
        ov.z = acc2 * inv + bv.z;
        ov.w = acc3 * inv + bv.w;
        *(float4*)(out + o) = ov;
    }
}

extern "C" void kernel_launch(void* const* d_in, const int* in_sizes, int n_in,
                              void* d_out, int out_size, void* d_ws, size_t ws_size,
                              hipStream_t stream) {
    const float* x    = (const float*)d_in[0];
    const float* adj  = (const float*)d_in[1];
    const int*   erow = (const int*)d_in[2];
    const int*   ecol = (const int*)d_in[3];
    const float* Wmap = (const float*)d_in[4];
    const float* w1   = (const float*)d_in[5];
    const float* b1   = (const float*)d_in[6];
    const float* w2   = (const float*)d_in[7];
    const float* b2   = (const float*)d_in[8];
    const float* kern = (const float*)d_in[9];
    const float* bias = (const float*)d_in[10];
    float* out = (float*)d_out;

    int n  = in_sizes[0] / D;        // 100000
    int ne = in_sizes[1];            // 1600000
    int nbuk = (n + 255) >> 8;       // 391
    int nw = (ne + CH - 1) / CH;     // 196

    char* ws = (char*)d_ws;
    size_t off = 0;
    auto alloc = [&](size_t bytes) {
        void* p = ws + off;
        off += (bytes + 255) & ~255ull;
        return p;
    };
    // recs (int2 per edge, 12.8MB) aliases valbf (bf16 n*128, 25.6MB):
    // recs is dead once k_bucket completes; k_value_gemm runs after it.
    unsigned short* valbf = (unsigned short*)alloc((size_t)n * D * sizeof(unsigned short));
    int2*     recs    = (int2*)valbf;
    int2*     csr     = (int2*)alloc((size_t)ne * sizeof(int2));
    int*      rowptr  = (int*)alloc(((size_t)n + 1) * sizeof(int));
    int*      bstart  = (int*)alloc(((size_t)nbuk + 1) * sizeof(int));
    unsigned* cnt_matT = (unsigned*)alloc((size_t)nw * nbuk * sizeof(unsigned));
    unsigned* off_matT = (unsigned*)alloc((size_t)nw * nbuk * sizeof(unsigned));
    float*    sa1     = (float*)alloc((size_t)n * sizeof(float));
    float*    sa2     = (float*)alloc((size_t)n * sizeof(float));
    unsigned short* kTbf = (unsigned short*)alloc((size_t)144 * D * sizeof(unsigned short));

    k_prep<<<1, 256, 0, stream>>>(Wmap, w1, w2, kern, kTbf);
    k_count<<<nw, 256, 0, stream>>>(erow, cnt_matT, ne, nbuk, nw);
    k_scanb<<<1, 512, 0, stream>>>(cnt_matT, off_matT, bstart, nw, nbuk, ne);
    k_binscatter<<<nw, 256, 0, stream>>>(erow, ecol, adj, off_matT, recs, ne, nbuk, nw);
    k_bucket<<<nbuk, 256, 0, stream>>>(recs, bstart, rowptr, csr, n, ne);
    k_value_gemm<<<(n + BM - 1) / BM, 256, 0, stream>>>(x, kTbf, b1, b2,
                                                        valbf, sa1, sa2, n);
    k_row_attn<<<(n + 3) / 4, 256, 0, stream>>>(rowptr, csr, sa1, sa2,
                                                valbf, bias, out, n);
}

// Round 7
// 205.054 us; speedup vs baseline: 1.5114x; 1.5114x over previous
//
#include <hip/hip_runtime.h>

#define D 128
#define ALPHA 0.2f
#define CH 8192          // edges per chunk for count/binscatter
#define MAXB 512         // >= nbuk (391)

typedef __attribute__((ext_vector_type(8))) short bf16x8;
typedef __attribute__((ext_vector_type(4))) float f32x4;

__device__ __forceinline__ unsigned short f32_to_bf16(float f) {
    unsigned u = __float_as_uint(f);
    unsigned r = u + 0x7FFFu + ((u >> 16) & 1u);   // round-to-nearest-even
    return (unsigned short)(r >> 16);
}
__device__ __forceinline__ float bf16lo(unsigned u) {
    return __uint_as_float(u << 16);
}
__device__ __forceinline__ float bf16hi(unsigned u) {
    return __uint_as_float(u & 0xFFFF0000u);
}

// Build kTbf[144][128] bf16 (rows 0..127 = kernel^T, 128/129 = W_map@w1/w2),
// and zero the bucket-total array (ws is poisoned, not zeroed, by harness).
__global__ __launch_bounds__(256) void k_prep(
        const float* __restrict__ Wmap, const float* __restrict__ w1,
        const float* __restrict__ w2, const float* __restrict__ kern,
        unsigned short* __restrict__ kTbf, unsigned* __restrict__ btot,
        int nbuk) {
    int t = threadIdx.x;
    int lane = t & 63, wv = t >> 6;
    for (int i = t; i < nbuk; i += 256) btot[i] = 0u;
    float w1a = w1[lane], w1b = w1[64 + lane];
    float w2a = w2[lane], w2b = w2[64 + lane];
    for (int r = 0; r < 32; ++r) {
        int row = wv * 32 + r;
        float xa = Wmap[row * D + lane], xb = Wmap[row * D + 64 + lane];
        float s1 = xa * w1a + xb * w1b;
        float s2 = xa * w2a + xb * w2b;
        #pragma unroll
        for (int off = 32; off; off >>= 1) {
            s1 += __shfl_xor(s1, off);
            s2 += __shfl_xor(s2, off);
        }
        if (lane == 0) {
            kTbf[128 * D + row] = f32_to_bf16(s1);
            kTbf[129 * D + row] = f32_to_bf16(s2);
        }
    }
    for (int idx = t; idx < D * D; idx += 256) {      // kernel^T
        int k = idx >> 7, c = idx & 127;
        kTbf[c * D + k] = f32_to_bf16(kern[idx]);
    }
    for (int idx = 130 * D + t; idx < 144 * D; idx += 256) kTbf[idx] = 0;
}

// per-chunk LDS histogram -> global bucket totals; bucket = row >> 8
__global__ __launch_bounds__(256) void k_count(
        const int* __restrict__ erow, unsigned* __restrict__ btot,
        int ne, int nbuk) {
    __shared__ unsigned cl[MAXB];
    int wg = blockIdx.x, t = threadIdx.x;
    for (int i = t; i < nbuk; i += 256) cl[i] = 0u;
    __syncthreads();
    int base = wg * CH;
    int lim = min(CH, ne - base);
    for (int i = t; i < lim; i += 256)
        atomicAdd(&cl[erow[base + i] >> 8], 1u);
    __syncthreads();
    for (int i = t; i < nbuk; i += 256)
        if (cl[i]) atomicAdd(&btot[i], cl[i]);
}

// single block: exclusive scan of 391 bucket totals -> bstart, cursor
__global__ __launch_bounds__(512) void k_scanb(
        const unsigned* __restrict__ btot, int* __restrict__ bstart,
        unsigned* __restrict__ cursor, int nbuk, int ne) {
    __shared__ unsigned tot[512];
    int t = threadIdx.x;
    unsigned s = (t < nbuk) ? btot[t] : 0u;
    tot[t] = s;
    __syncthreads();
    for (int off = 1; off < 512; off <<= 1) {
        unsigned add = (t >= off) ? tot[t - off] : 0u;
        __syncthreads();
        tot[t] += add;
        __syncthreads();
    }
    unsigned base = tot[t] - s;  // exclusive
    if (t < nbuk) {
        bstart[t] = (int)base;
        cursor[t] = base;
    }
    if (t == 0) bstart[nbuk] = ne;
}

// count chunk in LDS, reserve per-bucket slices via global cursor, scatter
// packed {(rlocal<<24)|col, adj_bits} records.
__global__ __launch_bounds__(256) void k_binscatter(
        const int* __restrict__ erow, const int* __restrict__ ecol,
        const float* __restrict__ adj, unsigned* __restrict__ cursor,
        int2* __restrict__ recs, int ne, int nbuk) {
    __shared__ unsigned cl[MAXB];
    int wg = blockIdx.x, t = threadIdx.x;
    for (int i = t; i < nbuk; i += 256) cl[i] = 0u;
    __syncthreads();
    int base = wg * CH;
    int lim = min(CH, ne - base);
    for (int i = t; i < lim; i += 256)
        atomicAdd(&cl[erow[base + i] >> 8], 1u);
    __syncthreads();
    for (int i = t; i < nbuk; i += 256) {
        unsigned c = cl[i];
        cl[i] = c ? atomicAdd(&cursor[i], c) : 0u;   // reserve [base, base+c)
    }
    __syncthreads();
    for (int i = t; i < lim; i += 256) {
        int k = base + i;
        int r = erow[k];
        unsigned pos = atomicAdd(&cl[r >> 8], 1u);   // LDS fill within slice
        recs[pos] = make_int2(
            (int)(((unsigned)(r & 255) << 24) | (unsigned)ecol[k]),
            __float_as_int(adj[k]));
    }
}

// WG per bucket: per-row counts+scan in LDS -> rowptr; scatter {col,adj} into
// the bucket's contiguous CSR window (single-XCD L2-resident writes).
__global__ __launch_bounds__(256) void k_bucket(
        const int2* __restrict__ recs, const int* __restrict__ bstart,
        int* __restrict__ rowptr, int2* __restrict__ csr, int n, int ne) {
    __shared__ unsigned cntL[256], startL[256], fillL[256];
    int b = blockIdx.x, t = threadIdx.x;
    int rb0 = b << 8;
    int s = bstart[b], e = bstart[b + 1];
    cntL[t] = 0u;
    fillL[t] = 0u;
    __syncthreads();
    for (int i = s + t; i < e; i += 256)
        atomicAdd(&cntL[((unsigned)recs[i].x) >> 24], 1u);
    __syncthreads();
    unsigned v = cntL[t];
    startL[t] = v;
    __syncthreads();
    for (int off = 1; off < 256; off <<= 1) {
        unsigned add = (t >= off) ? startL[t - off] : 0u;
        __syncthreads();
        startL[t] += add;
        __syncthreads();
    }
    unsigned myStart = startL[t] - v;  // exclusive within bucket
    startL[t] = myStart;
    if (rb0 + t < n) rowptr[rb0 + t] = s + (int)myStart;
    if (b == 0 && t == 0) rowptr[n] = ne;
    __syncthreads();
    for (int i = s + t; i < e; i += 256) {
        int2 rc = recs[i];
        unsigned r = ((unsigned)rc.x) >> 24;
        unsigned p = atomicAdd(&fillL[r], 1u);
        csr[s + (int)startL[r] + (int)p] =
            make_int2(rc.x & 0x00FFFFFF, rc.y);
    }
}

// MFMA value-GEMM: valbf[n][128] = bf16(x @ kernel); 9th col-block computes
// sa1/sa2 (u1,u2 packed as B columns 128,129). 64 rows/block, 4 waves.
#define BM 64
#define NBLK 9
__global__ __launch_bounds__(256) void k_value_gemm(
        const float* __restrict__ x, const unsigned short* __restrict__ kTbf,
        const float* __restrict__ b1, const float* __restrict__ b2,
        unsigned short* __restrict__ valbf,
        float* __restrict__ sa1, float* __restrict__ sa2, int n) {
    __shared__ unsigned short As[BM * D];          // 16 KB, swizzled
    __shared__ unsigned short Bs[NBLK * 16 * D];   // 36 KB, swizzled
    int t = threadIdx.x;
    int rowbase = blockIdx.x * BM;
    for (int idx = t; idx < BM * 32; idx += 256) {    // float4 chunks
        int r = idx >> 5, k4 = (idx & 31) << 2;
        unsigned v0 = 0, v1 = 0;
        int grow = rowbase + r;
        if (grow < n) {
            float4 f = *(const float4*)(x + (size_t)grow * D + k4);
            v0 = (unsigned)f32_to_bf16(f.x) | ((unsigned)f32_to_bf16(f.y) << 16);
            v1 = (unsigned)f32_to_bf16(f.z) | ((unsigned)f32_to_bf16(f.w) << 16);
        }
        unsigned byte = (unsigned)(r * 256 + k4 * 2) ^ ((unsigned)(r & 7) << 4);
        *(uint2*)((char*)As + byte) = make_uint2(v0, v1);
    }
    for (int idx = t; idx < NBLK * 16 * 32; idx += 256) {  // 8B chunks
        int rowB = idx >> 5;
        uint2 v = ((const uint2*)kTbf)[idx];
        unsigned byte = (unsigned)(idx * 8) ^ ((unsigned)(rowB & 7) << 4);
        *(uint2*)((char*)Bs + byte) = v;
    }
    __syncthreads();

    int w = t >> 6, lane = t & 63;
    int arow = w * 16 + (lane & 15);
    f32x4 acc[NBLK];
    #pragma unroll
    for (int b = 0; b < NBLK; ++b) acc[b] = (f32x4){0.f, 0.f, 0.f, 0.f};
    #pragma unroll
    for (int ks = 0; ks < 4; ++ks) {
        int kk = ks * 32 + (lane >> 4) * 8;
        unsigned abyte = (unsigned)(arow * 256 + kk * 2) ^ ((unsigned)(arow & 7) << 4);
        bf16x8 af = *(const bf16x8*)((const char*)As + abyte);
        #pragma unroll
        for (int cb = 0; cb < NBLK; ++cb) {
            int brow = cb * 16 + (lane & 15);
            unsigned bbyte = (unsigned)(brow * 256 + kk * 2) ^ ((unsigned)(brow & 7) << 4);
            bf16x8 bfr = *(const bf16x8*)((const char*)Bs + bbyte);
            acc[cb] = __builtin_amdgcn_mfma_f32_16x16x32_bf16(af, bfr, acc[cb], 0, 0, 0);
        }
    }
    int col = lane & 15;
    int rbase2 = rowbase + w * 16 + (lane >> 4) * 4;
    #pragma unroll
    for (int cb = 0; cb < 8; ++cb) {
        #pragma unroll
        for (int i = 0; i < 4; ++i) {
            int grow = rbase2 + i;
            if (grow < n)
                valbf[(size_t)grow * D + cb * 16 + col] = f32_to_bf16(acc[cb][i]);
        }
    }
    if (col < 2) {   // cb=8: col0 = sa1, col1 = sa2
        float bb = (col == 0) ? b1[0] : b2[0];
        float* dst = (col == 0) ? sa1 : sa2;
        #pragma unroll
        for (int i = 0; i < 4; ++i) {
            int grow = rbase2 + i;
            if (grow < n) dst[grow] = acc[8][i] + bb;
        }
    }
}

// one wave per row: single-pass online-softmax SpMM over bf16 value rows.
__global__ __launch_bounds__(256) void k_row_attn(
        const int* __restrict__ rowptr, const int2* __restrict__ csr,
        const float* __restrict__ sa1, const float* __restrict__ sa2,
        const unsigned short* __restrict__ valbf,
        const float* __restrict__ bias, float* __restrict__ out, int n) {
    int wid = (blockIdx.x * 256 + threadIdx.x) >> 6;
    int lane = threadIdx.x & 63;
    if (wid >= n) return;
    int start = rowptr[wid], end = rowptr[wid + 1];
    float sa1r = sa1[wid];
    int half = lane >> 5, sub = lane & 31;

    float m = -INFINITY, dsum = 0.f;
    float acc0 = 0.f, acc1 = 0.f, acc2 = 0.f, acc3 = 0.f;

    for (int base = start; base < end; base += 64) {
        int k = base + lane;
        int cnt = min(64, end - base);
        float s = -INFINITY;
        int c = 0;
        if (k < end) {
            int2 ca = csr[k];
            c = ca.x;
            float a = __int_as_float(ca.y);
            s = a * sa1r + a * sa2[c];
            s = (s >= 0.f) ? s : ALPHA * s;
        }
        float bm = s;
        #pragma unroll
        for (int off = 32; off; off >>= 1) bm = fmaxf(bm, __shfl_xor(bm, off));
        float newm = fmaxf(m, bm);
        float scale = __expf(m - newm);    // first block: exp(-inf)=0
        dsum *= scale;
        acc0 *= scale; acc1 *= scale; acc2 *= scale; acc3 *= scale;
        m = newm;
        float p = 0.f;
        if (k < end) { p = __expf(s - m); dsum += p; }

        for (int j = 0; j < cnt; j += 8) {
            int e0 = j + half,     e1 = j + 2 + half;
            int e2 = j + 4 + half, e3 = j + 6 + half;
            float p0 = __shfl(p, e0); int c0 = __shfl(c, e0);
            float p1 = __shfl(p, e1); int c1 = __shfl(c, e1);
            float p2 = __shfl(p, e2); int c2 = __shfl(c, e2);
            float p3 = __shfl(p, e3); int c3 = __shfl(c, e3);
            if (e0 >= cnt) { p0 = 0.f; c0 = 0; }
            if (e1 >= cnt) { p1 = 0.f; c1 = 0; }
            if (e2 >= cnt) { p2 = 0.f; c2 = 0; }
            if (e3 >= cnt) { p3 = 0.f; c3 = 0; }
            uint2 q0 = ((const uint2*)(valbf + (size_t)c0 * D))[sub];
            uint2 q1 = ((const uint2*)(valbf + (size_t)c1 * D))[sub];
            uint2 q2 = ((const uint2*)(valbf + (size_t)c2 * D))[sub];
            uint2 q3 = ((const uint2*)(valbf + (size_t)c3 * D))[sub];
            acc0 += p0 * bf16lo(q0.x); acc1 += p0 * bf16hi(q0.x);
            acc2 += p0 * bf16lo(q0.y); acc3 += p0 * bf16hi(q0.y);
            acc0 += p1 * bf16lo(q1.x); acc1 += p1 * bf16hi(q1.x);
            acc2 += p1 * bf16lo(q1.y); acc3 += p1 * bf16hi(q1.y);
            acc0 += p2 * bf16lo(q2.x); acc1 += p2 * bf16hi(q2.x);
            acc2 += p2 * bf16lo(q2.y); acc3 += p2 * bf16hi(q2.y);
            acc0 += p3 * bf16lo(q3.x); acc1 += p3 * bf16hi(q3.x);
            acc2 += p3 * bf16lo(q3.y); acc3 += p3 * bf16hi(q3.y);
        }
    }
    acc0 += __shfl_xor(acc0, 32);
    acc1 += __shfl_xor(acc1, 32);
    acc2 += __shfl_xor(acc2, 32);
    acc3 += __shfl_xor(acc3, 32);
    #pragma unroll
    for (int off = 32; off; off >>= 1) dsum += __shfl_xor(dsum, off);
    float inv = (dsum > 0.f) ? 1.f / dsum : 0.f;   // empty row -> out = bias

    if (half == 0) {
        size_t o = (size_t)wid * D + (size_t)sub * 4;
        float4 bv = *(const float4*)(bias + o);
        float4 ov;
        ov.x = acc0 * inv + bv.x;
        ov.y = acc1 * inv + bv.y;
        ov.z = acc2 * inv + bv.z;
        ov.w = acc3 * inv + bv.w;
        *(float4*)(out + o) = ov;
    }
}

extern "C" void kernel_launch(void* const* d_in, const int* in_sizes, int n_in,
                              void* d_out, int out_size, void* d_ws, size_t ws_size,
                              hipStream_t stream) {
    const float* x    = (const float*)d_in[0];
    const float* adj  = (const float*)d_in[1];
    const int*   erow = (const int*)d_in[2];
    const int*   ecol = (const int*)d_in[3];
    const float* Wmap = (const float*)d_in[4];
    const float* w1   = (const float*)d_in[5];
    const float* b1   = (const float*)d_in[6];
    const float* w2   = (const float*)d_in[7];
    const float* b2   = (const float*)d_in[8];
    const float* kern = (const float*)d_in[9];
    const float* bias = (const float*)d_in[10];
    float* out = (float*)d_out;

    int n  = in_sizes[0] / D;        // 100000
    int ne = in_sizes[1];            // 1600000
    int nbuk = (n + 255) >> 8;       // 391
    int nw = (ne + CH - 1) / CH;     // 196

    char* ws = (char*)d_ws;
    size_t off = 0;
    auto alloc = [&](size_t bytes) {
        void* p = ws + off;
        off += (bytes + 255) & ~255ull;
        return p;
    };
    // recs (int2 per edge, 12.8MB) aliases valbf (bf16 n*128, 25.6MB):
    // recs is dead once k_bucket completes; k_value_gemm runs after it.
    unsigned short* valbf = (unsigned short*)alloc((size_t)n * D * sizeof(unsigned short));
    int2*     recs    = (int2*)valbf;
    int2*     csr     = (int2*)alloc((size_t)ne * sizeof(int2));
    int*      rowptr  = (int*)alloc(((size_t)n + 1) * sizeof(int));
    int*      bstart  = (int*)alloc(((size_t)nbuk + 1) * sizeof(int));
    unsigned* btot    = (unsigned*)alloc((size_t)nbuk * sizeof(unsigned));
    unsigned* cursor  = (unsigned*)alloc((size_t)nbuk * sizeof(unsigned));
    float*    sa1     = (float*)alloc((size_t)n * sizeof(float));
    float*    sa2     = (float*)alloc((size_t)n * sizeof(float));
    unsigned short* kTbf = (unsigned short*)alloc((size_t)144 * D * sizeof(unsigned short));

    k_prep<<<1, 256, 0, stream>>>(Wmap, w1, w2, kern, kTbf, btot, nbuk);
    k_count<<<nw, 256, 0, stream>>>(erow, btot, ne, nbuk);
    k_scanb<<<1, 512, 0, stream>>>(btot, bstart, cursor, nbuk, ne);
    k_binscatter<<<nw, 256, 0, stream>>>(erow, ecol, adj, cursor, recs, ne, nbuk);
    k_bucket<<<nbuk, 256, 0, stream>>>(recs, bstart, rowptr, csr, n, ne);
    k_value_gemm<<<(n + BM - 1) / BM, 256, 0, stream>>>(x, kTbf, b1, b2,
                                                        valbf, sa1, sa2, n);
    k_row_attn<<<(n + 3) / 4, 256, 0, stream>>>(rowptr, csr, sa1, sa2,
                                                valbf, bias, out, n);
}

// Round 8
// 192.253 us; speedup vs baseline: 1.6120x; 1.0666x over previous
//
#include <hip/hip_runtime.h>

#define D 128
#define ALPHA 0.2f
#define CH 8192          // edges per chunk for count/binscatter
#define MAXB 512         // >= nbuk (391)
#define BM 64
#define NBLK 9

typedef __attribute__((ext_vector_type(8))) short bf16x8;
typedef __attribute__((ext_vector_type(4))) float f32x4;

__device__ __forceinline__ unsigned short f32_to_bf16(float f) {
    unsigned u = __float_as_uint(f);
    unsigned r = u + 0x7FFFu + ((u >> 16) & 1u);   // round-to-nearest-even
    return (unsigned short)(r >> 16);
}
__device__ __forceinline__ float bf16lo(unsigned u) {
    return __uint_as_float(u << 16);
}
__device__ __forceinline__ float bf16hi(unsigned u) {
    return __uint_as_float(u & 0xFFFF0000u);
}

// Build kTbf[144][128] bf16 (rows 0..127 = kernel^T, 128/129 = W_map@w1/w2),
// and zero the bucket-total array (ws is poisoned, not zeroed, by harness).
__global__ __launch_bounds__(256) void k_prep(
        const float* __restrict__ Wmap, const float* __restrict__ w1,
        const float* __restrict__ w2, const float* __restrict__ kern,
        unsigned short* __restrict__ kTbf, unsigned* __restrict__ btot,
        int nbuk) {
    int t = threadIdx.x;
    int lane = t & 63, wv = t >> 6;
    for (int i = t; i < nbuk; i += 256) btot[i] = 0u;
    float w1a = w1[lane], w1b = w1[64 + lane];
    float w2a = w2[lane], w2b = w2[64 + lane];
    for (int r = 0; r < 32; ++r) {
        int row = wv * 32 + r;
        float xa = Wmap[row * D + lane], xb = Wmap[row * D + 64 + lane];
        float s1 = xa * w1a + xb * w1b;
        float s2 = xa * w2a + xb * w2b;
        #pragma unroll
        for (int off = 32; off; off >>= 1) {
            s1 += __shfl_xor(s1, off);
            s2 += __shfl_xor(s2, off);
        }
        if (lane == 0) {
            kTbf[128 * D + row] = f32_to_bf16(s1);
            kTbf[129 * D + row] = f32_to_bf16(s2);
        }
    }
    for (int idx = t; idx < D * D; idx += 256) {      // kernel^T
        int k = idx >> 7, c = idx & 127;
        kTbf[c * D + k] = f32_to_bf16(kern[idx]);
    }
    for (int idx = 130 * D + t; idx < 144 * D; idx += 256) kTbf[idx] = 0;
}

// per-chunk LDS histogram -> global bucket totals; bucket = row >> 8
__global__ __launch_bounds__(256) void k_count(
        const int* __restrict__ erow, unsigned* __restrict__ btot,
        int ne, int nbuk) {
    __shared__ unsigned cl[MAXB];
    int wg = blockIdx.x, t = threadIdx.x;
    for (int i = t; i < nbuk; i += 256) cl[i] = 0u;
    __syncthreads();
    int base = wg * CH;
    int lim = min(CH, ne - base);
    int nv = lim >> 2;
    const int4* e4 = (const int4*)(erow + base);
    for (int i = t; i < nv; i += 256) {
        int4 v = e4[i];
        atomicAdd(&cl[v.x >> 8], 1u);
        atomicAdd(&cl[v.y >> 8], 1u);
        atomicAdd(&cl[v.z >> 8], 1u);
        atomicAdd(&cl[v.w >> 8], 1u);
    }
    for (int i = (nv << 2) + t; i < lim; i += 256)
        atomicAdd(&cl[erow[base + i] >> 8], 1u);
    __syncthreads();
    for (int i = t; i < nbuk; i += 256)
        if (cl[i]) atomicAdd(&btot[i], cl[i]);
}

// single block: exclusive scan of bucket totals -> bstart, cursor
__global__ __launch_bounds__(512) void k_scanb(
        const unsigned* __restrict__ btot, int* __restrict__ bstart,
        unsigned* __restrict__ cursor, int nbuk, int ne) {
    __shared__ unsigned tot[512];
    int t = threadIdx.x;
    unsigned s = (t < nbuk) ? btot[t] : 0u;
    tot[t] = s;
    __syncthreads();
    for (int off = 1; off < 512; off <<= 1) {
        unsigned add = (t >= off) ? tot[t - off] : 0u;
        __syncthreads();
        tot[t] += add;
        __syncthreads();
    }
    unsigned base = tot[t] - s;  // exclusive
    if (t < nbuk) {
        bstart[t] = (int)base;
        cursor[t] = base;
    }
    if (t == 0) bstart[nbuk] = ne;
}

// Fused: blocks [0,ngemm) = MFMA value-GEMM; blocks [ngemm,..) = binscatter.
// The two halves touch disjoint data and are independent -> run concurrently.
__global__ __launch_bounds__(256) void k_fuseB(
        const float* __restrict__ x, const unsigned short* __restrict__ kTbf,
        const float* __restrict__ b1, const float* __restrict__ b2,
        unsigned short* __restrict__ valbf,
        float* __restrict__ sa1, float* __restrict__ sa2, int n,
        const int* __restrict__ erow, const int* __restrict__ ecol,
        const float* __restrict__ adj, unsigned* __restrict__ cursor,
        int2* __restrict__ recs, int ne, int nbuk, int ngemm) {
    __shared__ __align__(16) char smem[53248];   // max(gemm 52KB, cl 2KB)
    int t = threadIdx.x;
    if ((int)blockIdx.x < ngemm) {
        // ---- MFMA value-GEMM: valbf = bf16(x @ kernel), sa1/sa2 fused ----
        unsigned short* As = (unsigned short*)smem;            // 16 KB
        unsigned short* Bs = As + BM * D;                      // 36 KB
        int rowbase = blockIdx.x * BM;
        for (int idx = t; idx < BM * 32; idx += 256) {    // float4 chunks
            int r = idx >> 5, k4 = (idx & 31) << 2;
            unsigned v0 = 0, v1 = 0;
            int grow = rowbase + r;
            if (grow < n) {
                float4 f = *(const float4*)(x + (size_t)grow * D + k4);
                v0 = (unsigned)f32_to_bf16(f.x) | ((unsigned)f32_to_bf16(f.y) << 16);
                v1 = (unsigned)f32_to_bf16(f.z) | ((unsigned)f32_to_bf16(f.w) << 16);
            }
            unsigned byte = (unsigned)(r * 256 + k4 * 2) ^ ((unsigned)(r & 7) << 4);
            *(uint2*)((char*)As + byte) = make_uint2(v0, v1);
        }
        for (int idx = t; idx < NBLK * 16 * 32; idx += 256) {  // 8B chunks
            int rowB = idx >> 5;
            uint2 v = ((const uint2*)kTbf)[idx];
            unsigned byte = (unsigned)(idx * 8) ^ ((unsigned)(rowB & 7) << 4);
            *(uint2*)((char*)Bs + byte) = v;
        }
        __syncthreads();

        int w = t >> 6, lane = t & 63;
        int arow = w * 16 + (lane & 15);
        f32x4 acc[NBLK];
        #pragma unroll
        for (int b = 0; b < NBLK; ++b) acc[b] = (f32x4){0.f, 0.f, 0.f, 0.f};
        #pragma unroll
        for (int ks = 0; ks < 4; ++ks) {
            int kk = ks * 32 + (lane >> 4) * 8;
            unsigned abyte = (unsigned)(arow * 256 + kk * 2) ^ ((unsigned)(arow & 7) << 4);
            bf16x8 af = *(const bf16x8*)((const char*)As + abyte);
            #pragma unroll
            for (int cb = 0; cb < NBLK; ++cb) {
                int brow = cb * 16 + (lane & 15);
                unsigned bbyte = (unsigned)(brow * 256 + kk * 2) ^ ((unsigned)(brow & 7) << 4);
                bf16x8 bfr = *(const bf16x8*)((const char*)Bs + bbyte);
                acc[cb] = __builtin_amdgcn_mfma_f32_16x16x32_bf16(af, bfr, acc[cb], 0, 0, 0);
            }
        }
        int col = lane & 15;
        int rbase2 = rowbase + w * 16 + (lane >> 4) * 4;
        #pragma unroll
        for (int cb = 0; cb < 8; ++cb) {
            #pragma unroll
            for (int i = 0; i < 4; ++i) {
                int grow = rbase2 + i;
                if (grow < n)
                    valbf[(size_t)grow * D + cb * 16 + col] = f32_to_bf16(acc[cb][i]);
            }
        }
        if (col < 2) {   // cb=8: col0 = sa1, col1 = sa2
            float bb = (col == 0) ? b1[0] : b2[0];
            float* dst = (col == 0) ? sa1 : sa2;
            #pragma unroll
            for (int i = 0; i < 4; ++i) {
                int grow = rbase2 + i;
                if (grow < n) dst[grow] = acc[8][i] + bb;
            }
        }
    } else {
        // ---- binscatter: reserve per-bucket slices, scatter packed recs ----
        unsigned* cl = (unsigned*)smem;
        int wg = (int)blockIdx.x - ngemm;
        for (int i = t; i < nbuk; i += 256) cl[i] = 0u;
        __syncthreads();
        int base = wg * CH;
        int lim = min(CH, ne - base);
        int nv = lim >> 2;
        const int4* e4 = (const int4*)(erow + base);
        for (int i = t; i < nv; i += 256) {
            int4 v = e4[i];
            atomicAdd(&cl[v.x >> 8], 1u);
            atomicAdd(&cl[v.y >> 8], 1u);
            atomicAdd(&cl[v.z >> 8], 1u);
            atomicAdd(&cl[v.w >> 8], 1u);
        }
        for (int i = (nv << 2) + t; i < lim; i += 256)
            atomicAdd(&cl[erow[base + i] >> 8], 1u);
        __syncthreads();
        for (int i = t; i < nbuk; i += 256) {
            unsigned c = cl[i];
            cl[i] = c ? atomicAdd(&cursor[i], c) : 0u;   // reserve slice
        }
        __syncthreads();
        const int4* c4 = (const int4*)(ecol + base);
        const float4* a4 = (const float4*)(adj + base);
        for (int i = t; i < nv; i += 256) {
            int4 r = e4[i];
            int4 c = c4[i];
            float4 a = a4[i];
            unsigned p0 = atomicAdd(&cl[r.x >> 8], 1u);
            recs[p0] = make_int2((int)(((unsigned)(r.x & 255) << 24) | (unsigned)c.x), __float_as_int(a.x));
            unsigned p1 = atomicAdd(&cl[r.y >> 8], 1u);
            recs[p1] = make_int2((int)(((unsigned)(r.y & 255) << 24) | (unsigned)c.y), __float_as_int(a.y));
            unsigned p2 = atomicAdd(&cl[r.z >> 8], 1u);
            recs[p2] = make_int2((int)(((unsigned)(r.z & 255) << 24) | (unsigned)c.z), __float_as_int(a.z));
            unsigned p3 = atomicAdd(&cl[r.w >> 8], 1u);
            recs[p3] = make_int2((int)(((unsigned)(r.w & 255) << 24) | (unsigned)c.w), __float_as_int(a.w));
        }
        for (int i = (nv << 2) + t; i < lim; i += 256) {
            int k = base + i;
            int r = erow[k];
            unsigned pos = atomicAdd(&cl[r >> 8], 1u);
            recs[pos] = make_int2(
                (int)(((unsigned)(r & 255) << 24) | (unsigned)ecol[k]),
                __float_as_int(adj[k]));
        }
    }
}

// WG per bucket: per-row counts+scan in LDS -> rowptr; scatter {col,adj} into
// the bucket's contiguous CSR window (single-XCD L2-resident writes).
__global__ __launch_bounds__(256) void k_bucket(
        const int2* __restrict__ recs, const int* __restrict__ bstart,
        int* __restrict__ rowptr, int2* __restrict__ csr, int n, int ne) {
    __shared__ unsigned cntL[256], startL[256], fillL[256];
    int b = blockIdx.x, t = threadIdx.x;
    int rb0 = b << 8;
    int s = bstart[b], e = bstart[b + 1];
    cntL[t] = 0u;
    fillL[t] = 0u;
    __syncthreads();
    for (int i = s + t; i < e; i += 256)
        atomicAdd(&cntL[((unsigned)recs[i].x) >> 24], 1u);
    __syncthreads();
    unsigned v = cntL[t];
    startL[t] = v;
    __syncthreads();
    for (int off = 1; off < 256; off <<= 1) {
        unsigned add = (t >= off) ? startL[t - off] : 0u;
        __syncthreads();
        startL[t] += add;
        __syncthreads();
    }
    unsigned myStart = startL[t] - v;  // exclusive within bucket
    startL[t] = myStart;
    if (rb0 + t < n) rowptr[rb0 + t] = s + (int)myStart;
    if (b == 0 && t == 0) rowptr[n] = ne;
    __syncthreads();
    for (int i = s + t; i < e; i += 256) {
        int2 rc = recs[i];
        unsigned r = ((unsigned)rc.x) >> 24;
        unsigned p = atomicAdd(&fillL[r], 1u);
        csr[s + (int)startL[r] + (int)p] =
            make_int2(rc.x & 0x00FFFFFF, rc.y);
    }
}

// one wave per row: single-pass online-softmax SpMM over bf16 value rows.
// (p,c) staged in per-wave LDS once per 64-edge block; each 16-lane quarter
// handles one edge per step with a uint4 (16B) gather -> no shuffles/masks.
__global__ __launch_bounds__(256) void k_row_attn(
        const int* __restrict__ rowptr, const int2* __restrict__ csr,
        const float* __restrict__ sa1, const float* __restrict__ sa2,
        const unsigned short* __restrict__ valbf,
        const float* __restrict__ bias, float* __restrict__ out, int n) {
    __shared__ int2 pcL[4][64];
    int tid = threadIdx.x;
    int wv = tid >> 6, lane = tid & 63;
    int wid = (blockIdx.x << 2) + wv;
    if (wid >= n) return;
    int start = rowptr[wid], end = rowptr[wid + 1];
    float sa1r = sa1[wid];
    int quad = lane >> 4, sub = lane & 15;

    float m = -INFINITY, dsum = 0.f;
    float a[8];
    #pragma unroll
    for (int i = 0; i < 8; ++i) a[i] = 0.f;

    for (int base = start; base < end; base += 64) {
        int k = base + lane;
        int cnt = min(64, end - base);
        float s = -INFINITY;
        int c = 0;
        if (k < end) {
            int2 ca = csr[k];
            c = ca.x;
            float av = __int_as_float(ca.y);
            s = av * sa1r + av * sa2[c];
            s = (s >= 0.f) ? s : ALPHA * s;
        }
        float bm = s;
        #pragma unroll
        for (int off = 32; off; off >>= 1) bm = fmaxf(bm, __shfl_xor(bm, off));
        float newm = fmaxf(m, bm);
        float scale = __expf(m - newm);    // first block: exp(-inf)=0
        dsum *= scale;
        #pragma unroll
        for (int i = 0; i < 8; ++i) a[i] *= scale;
        m = newm;
        float p = 0.f;
        if (k < end) { p = __expf(s - m); dsum += p; }
        pcL[wv][lane] = make_int2(__float_as_int(p), c);  // pads: p=0,c=0

        int steps = (cnt + 3) >> 2;
        for (int j = 0; j < steps; ++j) {
            int2 pc = pcL[wv][(j << 2) + quad];   // uniform per quarter
            float pj = __int_as_float(pc.x);
            uint4 q = *(const uint4*)(valbf + ((size_t)pc.y << 7) + (sub << 3));
            a[0] += pj * bf16lo(q.x); a[1] += pj * bf16hi(q.x);
            a[2] += pj * bf16lo(q.y); a[3] += pj * bf16hi(q.y);
            a[4] += pj * bf16lo(q.z); a[5] += pj * bf16hi(q.z);
            a[6] += pj * bf16lo(q.w); a[7] += pj * bf16hi(q.w);
        }
    }
    #pragma unroll
    for (int i = 0; i < 8; ++i) {
        a[i] += __shfl_xor(a[i], 16);
        a[i] += __shfl_xor(a[i], 32);
    }
    #pragma unroll
    for (int off = 32; off; off >>= 1) dsum += __shfl_xor(dsum, off);
    float inv = (dsum > 0.f) ? 1.f / dsum : 0.f;   // empty row -> out = bias

    if (quad == 0) {
        size_t o = ((size_t)wid << 7) + (sub << 3);
        float4 b0 = *(const float4*)(bias + o);
        float4 b1v = *(const float4*)(bias + o + 4);
        float4 o0 = make_float4(a[0] * inv + b0.x, a[1] * inv + b0.y,
                                a[2] * inv + b0.z, a[3] * inv + b0.w);
        float4 o1 = make_float4(a[4] * inv + b1v.x, a[5] * inv + b1v.y,
                                a[6] * inv + b1v.z, a[7] * inv + b1v.w);
        *(float4*)(out + o) = o0;
        *(float4*)(out + o + 4) = o1;
    }
}

extern "C" void kernel_launch(void* const* d_in, const int* in_sizes, int n_in,
                              void* d_out, int out_size, void* d_ws, size_t ws_size,
                              hipStream_t stream) {
    const float* x    = (const float*)d_in[0];
    const float* adj  = (const float*)d_in[1];
    const int*   erow = (const int*)d_in[2];
    const int*   ecol = (const int*)d_in[3];
    const float* Wmap = (const float*)d_in[4];
    const float* w1   = (const float*)d_in[5];
    const float* b1   = (const float*)d_in[6];
    const float* w2   = (const float*)d_in[7];
    const float* b2   = (const float*)d_in[8];
    const float* kern = (const float*)d_in[9];
    const float* bias = (const float*)d_in[10];
    float* out = (float*)d_out;

    int n  = in_sizes[0] / D;        // 100000
    int ne = in_sizes[1];            // 1600000
    int nbuk = (n + 255) >> 8;       // 391
    int nw = (ne + CH - 1) / CH;     // 196
    int ngemm = (n + BM - 1) / BM;   // 1563

    char* ws = (char*)d_ws;
    size_t off = 0;
    auto alloc = [&](size_t bytes) {
        void* p = ws + off;
        off += (bytes + 255) & ~255ull;
        return p;
    };
    unsigned short* valbf = (unsigned short*)alloc((size_t)n * D * sizeof(unsigned short));
    int2*     recs    = (int2*)alloc((size_t)ne * sizeof(int2));   // no longer aliased
    int2*     csr     = (int2*)alloc((size_t)ne * sizeof(int2));
    int*      rowptr  = (int*)alloc(((size_t)n + 1) * sizeof(int));
    int*      bstart  = (int*)alloc(((size_t)nbuk + 1) * sizeof(int));
    unsigned* btot    = (unsigned*)alloc((size_t)nbuk * sizeof(unsigned));
    unsigned* cursor  = (unsigned*)alloc((size_t)nbuk * sizeof(unsigned));
    float*    sa1     = (float*)alloc((size_t)n * sizeof(float));
    float*    sa2     = (float*)alloc((size_t)n * sizeof(float));
    unsigned short* kTbf = (unsigned short*)alloc((size_t)144 * D * sizeof(unsigned short));

    k_prep<<<1, 256, 0, stream>>>(Wmap, w1, w2, kern, kTbf, btot, nbuk);
    k_count<<<nw, 256, 0, stream>>>(erow, btot, ne, nbuk);
    k_scanb<<<1, 512, 0, stream>>>(btot, bstart, cursor, nbuk, ne);
    k_fuseB<<<ngemm + nw, 256, 0, stream>>>(x, kTbf, b1, b2, valbf, sa1, sa2, n,
                                            erow, ecol, adj, cursor, recs,
                                            ne, nbuk, ngemm);
    k_bucket<<<nbuk, 256, 0, stream>>>(recs, bstart, rowptr, csr, n, ne);
    k_row_attn<<<(n + 3) / 4, 256, 0, stream>>>(rowptr, csr, sa1, sa2,
                                                valbf, bias, out, n);
}